// Round 1
// 748.092 us; speedup vs baseline: 1.1843x; 1.1843x over previous
//
#include <hip/hip_runtime.h>
#include <stdint.h>

#define EPS 1e-3f

typedef _Float16 f16x8 __attribute__((ext_vector_type(8)));
typedef float f32x4 __attribute__((ext_vector_type(4)));
typedef float f32x16 __attribute__((ext_vector_type(16)));

// ---------------------------------------------------------------------------
// Setup: fold BN into scale/bias; prepack w_pos into 32x32x16-MFMA A-frags,
// u-packed contraction:  k = kap*8+j = (u = k>>2, y4 = k&3)
//   m = ol*16+kk, frag f = (w*23 + ss)*8 + rel  (rel = y-quad offset)
//   value = w_pos[kk][u][dy = 4*rel + y4 - 2w - ol][ss]  (0 if dy outside [0,23))
// ---------------------------------------------------------------------------
__global__ __launch_bounds__(256) void setup_kernel(
    const float* __restrict__ w_pos,
    const float* __restrict__ gq, const float* __restrict__ bq,
    const float* __restrict__ mq, const float* __restrict__ vq,
    const float* __restrict__ gv, const float* __restrict__ bv,
    const float* __restrict__ mv, const float* __restrict__ vvar,
    float* __restrict__ scale_bias, _Float16* __restrict__ Apack) {
  const int idx = blockIdx.x * 256 + threadIdx.x;
  if (idx < 384) {
    float sc, bi;
    if (idx < 64) {
      const float inv = gq[idx] * rsqrtf(vq[idx] + EPS);
      sc = inv; bi = bq[idx] - mq[idx] * inv;
    } else if (idx < 128) {
      sc = 1.f; bi = 0.f;  // k has no BN
    } else {
      const int o = idx - 128;
      const float inv = gv[o] * rsqrtf(vvar[o] + EPS);
      sc = inv; bi = bv[o] - mv[o] * inv;
    }
    scale_bias[idx] = sc;
    scale_bias[384 + idx] = bi;
  }
  if (idx < 376832) {  // 736 frags * 64 lanes * 8 halfs
    const int j = idx & 7;
    const int lane = (idx >> 3) & 63;
    const int f = idx >> 9;
    const int rel = f & 7;
    const int ss = (f >> 3) % 23;
    const int w = (f >> 3) / 23;
    const int m = lane & 31;
    const int kk = m & 15;
    const int ol = m >> 4;
    const int kap = lane >> 5;
    const int k = kap * 8 + j;
    const int u = k >> 2;
    const int y4 = k & 3;
    const int dy = 4 * rel + y4 - 2 * w - ol;
    float val = 0.f;
    if (dy >= 0 && dy < 23)
      val = w_pos[kk * 2116 + u * 529 + dy * 23 + ss];
    Apack[idx] = (_Float16)val;
  }
}

// ---------------------------------------------------------------------------
// Projection GEMM (unchanged)
// ---------------------------------------------------------------------------
__global__ __launch_bounds__(256) void proj_gemm(
    const float* __restrict__ x,
    const float* __restrict__ w_q, const float* __restrict__ w_k,
    const float* __restrict__ w_v,
    const float* __restrict__ scale_bias,
    float* __restrict__ proj) {
  const int b = blockIdx.z;
  const int ot = blockIdx.y;
  const int nBase = blockIdx.x * 64;
  const int tid = threadIdx.x;
  const int tx = tid & 15, ty = tid >> 4;

  const float* W;
  int oRow;
  if (ot == 0)      { W = w_q; oRow = 0; }
  else if (ot == 1) { W = w_k; oRow = 0; }
  else              { W = w_v; oRow = (ot - 2) * 64; }

  __shared__ float la[32][64];
  __shared__ float lb[32][64];

  float acc[4][4];
#pragma unroll
  for (int i = 0; i < 4; i++)
#pragma unroll
    for (int j = 0; j < 4; j++) acc[i][j] = 0.f;

  const int o_l = tid & 63;
  const int c4a = (tid >> 6) * 4;
  const int cb = tid >> 4;
  const int n4 = (tid & 15) * 4;

  for (int k0 = 0; k0 < 256; k0 += 32) {
    __syncthreads();
#pragma unroll
    for (int rr = 0; rr < 2; rr++) {
      const int c0 = c4a + rr * 16;
      const float4 wv4 = *(const float4*)&W[(size_t)(oRow + o_l) * 256 + k0 + c0];
      la[c0 + 0][o_l] = wv4.x;
      la[c0 + 1][o_l] = wv4.y;
      la[c0 + 2][o_l] = wv4.z;
      la[c0 + 3][o_l] = wv4.w;
    }
#pragma unroll
    for (int rr = 0; rr < 2; rr++) {
      const int c_l = cb + rr * 16;
      const float4 xv =
          *(const float4*)&x[((size_t)(b * 256 + k0 + c_l)) * 4096 + nBase + n4];
      *(float4*)&lb[c_l][n4] = xv;
    }
    __syncthreads();
#pragma unroll
    for (int kk = 0; kk < 32; kk++) {
      const float4 av = *(const float4*)&la[kk][ty * 4];
      const float4 bv = *(const float4*)&lb[kk][tx * 4];
      const float a[4] = {av.x, av.y, av.z, av.w};
      const float bb[4] = {bv.x, bv.y, bv.z, bv.w};
#pragma unroll
      for (int i = 0; i < 4; i++)
#pragma unroll
        for (int j = 0; j < 4; j++) acc[i][j] = fmaf(a[i], bb[j], acc[i][j]);
    }
  }

#pragma unroll
  for (int i = 0; i < 4; i++) {
    const int oG = ot * 64 + ty * 4 + i;
    const float sc = scale_bias[oG];
    const float bi = scale_bias[384 + oG];
    float4 r;
    r.x = fmaf(acc[i][0], sc, bi);
    r.y = fmaf(acc[i][1], sc, bi);
    r.z = fmaf(acc[i][2], sc, bi);
    r.w = fmaf(acc[i][3], sc, bi);
    *(float4*)&proj[((size_t)(b * 384 + oG)) * 4096 + nBase + tx * 4] = r;
  }
}

// ---------------------------------------------------------------------------
// Softmax (unchanged)
// ---------------------------------------------------------------------------
__global__ __launch_bounds__(256) void softmax_k(float* __restrict__ proj) {
  const int row = blockIdx.x;
  const int b = row >> 6, c = row & 63;
  float* p = proj + ((size_t)(b * 384 + 64 + c)) * 4096;
  const int tid = threadIdx.x;

  float4 v[4];
  float vmax = -3.4e38f;
#pragma unroll
  for (int i = 0; i < 4; i++) {
    v[i] = ((const float4*)p)[tid + i * 256];
    vmax = fmaxf(vmax, fmaxf(fmaxf(v[i].x, v[i].y), fmaxf(v[i].z, v[i].w)));
  }
#pragma unroll
  for (int off = 32; off > 0; off >>= 1) vmax = fmaxf(vmax, __shfl_xor(vmax, off));
  __shared__ float redm[4], reds[4];
  if ((tid & 63) == 0) redm[tid >> 6] = vmax;
  __syncthreads();
  vmax = fmaxf(fmaxf(redm[0], redm[1]), fmaxf(redm[2], redm[3]));

  float sum = 0.f;
#pragma unroll
  for (int i = 0; i < 4; i++) {
    v[i].x = expf(v[i].x - vmax); sum += v[i].x;
    v[i].y = expf(v[i].y - vmax); sum += v[i].y;
    v[i].z = expf(v[i].z - vmax); sum += v[i].z;
    v[i].w = expf(v[i].w - vmax); sum += v[i].w;
  }
#pragma unroll
  for (int off = 32; off > 0; off >>= 1) sum += __shfl_xor(sum, off);
  if ((tid & 63) == 0) reds[tid >> 6] = sum;
  __syncthreads();
  sum = reds[0] + reds[1] + reds[2] + reds[3];
  const float inv = 1.f / sum;
#pragma unroll
  for (int i = 0; i < 4; i++) {
    v[i].x *= inv; v[i].y *= inv; v[i].z *= inv; v[i].w *= inv;
    ((float4*)p)[tid + i * 256] = v[i];
  }
}

// ---------------------------------------------------------------------------
// Lc (unchanged)
// ---------------------------------------------------------------------------
__global__ __launch_bounds__(256) void lc_kernel(const float* __restrict__ proj,
                                                 float* __restrict__ Lc) {
  const int kk = blockIdx.x, b = blockIdx.y;
  const int tid = threadIdx.x;
  const int wave = tid >> 6, lane = tid & 63;
  float acc[16];
#pragma unroll
  for (int j = 0; j < 16; j++) acc[j] = 0.f;

  for (int u = 0; u < 4; u++) {
    const float* ks = proj + ((size_t)(b * 384 + 64 + u * 16 + kk)) * 4096;
    const float* vp = proj + ((size_t)(b * 384 + 128 + u * 64 + wave * 16)) * 4096;
    for (int m = lane; m < 4096; m += 64) {
      const float kvl = ks[m];
#pragma unroll
      for (int j = 0; j < 16; j++)
        acc[j] = fmaf(kvl, vp[(size_t)j * 4096 + m], acc[j]);
    }
  }
#pragma unroll
  for (int j = 0; j < 16; j++) {
#pragma unroll
    for (int off = 32; off > 0; off >>= 1) acc[j] += __shfl_xor(acc[j], off);
  }
  if (lane == 0) {
#pragma unroll
    for (int j = 0; j < 16; j++)
      Lc[(b * 16 + kk) * 64 + wave * 16 + j] = acc[j];
  }
}

// ---------------------------------------------------------------------------
// MFMA position-conv + Yp + Yc. Block = (dv, b). 32x32x16_f16, u-packed K:
//   m = ol*16+kk, n = 32 output cols, k = (u = k>>2, y4 = k&3).
// LDS: vL[x'][tau][u][y4], row = 22 quads * 16 + 8 pad = 360 halfs (720 B:
// lane stride 720B = 180 words -> uniform 8/bank spread on ds_read_b128).
// Per ss: <=21 ds_read_b128 stream 6 taus ahead of their MFMAs; per tau
// up to 4 MFMAs acc[t] += A[rel=tau-2t] * B[tau]. A[rel] for ss+1 is
// prefetched into the dead A[rel] register at tau = 14+rel.
// Zero-frag pruning (dy range 4rel+[-1,3]-2w misses [0,23)):
//   rel0 skipped for w>=2, rel6 for w==0, rel7 for w!=3  (-18.75% MFMA).
// Epilogue unchanged: q-contraction per lane, kappa-pair shfl reduce,
// coalesced 128B-line stores.
// ---------------------------------------------------------------------------
__global__ __launch_bounds__(256, 2) void lambda_conv(
    const float* __restrict__ proj, const _Float16* __restrict__ Apack,
    const float* __restrict__ Lc, const float* __restrict__ b_pos,
    float* __restrict__ out) {
  const int dv = blockIdx.x;
  const int b = blockIdx.y;
  const int tid = threadIdx.x;
  const int w = tid >> 6;          // wave: off pair base {2w, 2w+1}
  const int lane = tid & 63;
  const int n = lane & 31;         // output col within pass
  const int kap = lane >> 5;

  __shared__ __align__(16) _Float16 vL[86 * 360];  // 61920 B

  // zero LDS (halo + pad)
  {
    const uint4 z = {0u, 0u, 0u, 0u};
    for (int i = tid; i < (86 * 360 * 2) / 16; i += 256) ((uint4*)vL)[i] = z;
  }
  __syncthreads();

  // stage v (f32 -> f16), transposed + u-packed: vL[x+11][sy>>2][u][sy&3]
  {
    const float* vsec = proj + ((size_t)(b * 384 + 128 + dv)) * 4096;
    for (int idx = tid; idx < 4096; idx += 256) {
      const int u = idx >> 10, g = (idx >> 4) & 63, c4 = (idx & 15) * 4;
      const float4 vv = *(const float4*)&vsec[(size_t)u * 64 * 4096 + g * 64 + c4];
      const int sy = g + 11;
      const int qoff = (sy >> 2) * 16 + (u << 2) + (sy & 3);
      _Float16* base = &vL[(c4 + 11) * 360 + qoff];
      base[0 * 360] = (_Float16)vv.x;
      base[1 * 360] = (_Float16)vv.y;
      base[2 * 360] = (_Float16)vv.z;
      base[3 * 360] = (_Float16)vv.w;
    }
  }
  __syncthreads();

  // Lc + b_pos for this lane's 8 kk channels: kk_e = (e&3) + 8*(e>>2) + 4*kap
  float lcb[8];
#pragma unroll
  for (int e = 0; e < 8; e++) {
    const int kk = (e & 3) + 8 * (e >> 2) + 4 * kap;
    lcb[e] = Lc[(b * 16 + kk) * 64 + dv] + b_pos[kk];
  }

  const float* qsec = proj + ((size_t)(b * 384)) * 4096;
  const f16x8* Ap = (const f16x8*)Apack;
  const f16x8* Awl = Ap + (size_t)(w * 184) * 64 + lane;  // frag (ss*8+rel)*64

  const bool g0 = (w < 2);   // rel0 / tau0 live
  const bool g6 = (w != 0);  // rel6 / tau20 live
  const bool g7 = (w == 3);  // rel7 / tau21 live

  f16x8 A[8];
#pragma unroll
  for (int r = 0; r < 8; ++r) A[r] = (f16x8)(_Float16)0.f;
  if (g0) A[0] = Awl[0 * 64];
#pragma unroll
  for (int r = 1; r < 6; ++r) A[r] = Awl[r * 64];
  if (g6) A[6] = Awl[6 * 64];
  if (g7) A[7] = Awl[7 * 64];

#pragma unroll 1
  for (int pass = 0; pass < 2; ++pass) {
    f32x16 acc[8];
#pragma unroll
    for (int t = 0; t < 8; t++) acc[t] = (f32x16)0.f;

#pragma unroll 1
    for (int ss = 0; ss < 23; ++ss) {
      const int ssn = (ss == 22) ? 0 : ss + 1;  // pass-independent A stream
      const f16x8* Awn = Awl + (size_t)(ssn * 8) * 64;
      const _Float16* brow = &vL[(32 * pass + n + ss) * 360 + 8 * kap];

      f16x8 Bq[22];
      // prologue: taus 0..5
      if (g0) Bq[0] = *(const f16x8*)__builtin_assume_aligned(brow, 16);
#pragma unroll
      for (int tau = 1; tau < 6; ++tau)
        Bq[tau] = *(const f16x8*)__builtin_assume_aligned(brow + 16 * tau, 16);

#pragma unroll
      for (int tau = 0; tau < 22; ++tau) {
        // streaming prefetch, 6 taus ahead
        const int tpf = tau + 6;
        if (tpf < 22) {
          if (tpf == 20) {
            if (g6) Bq[20] = *(const f16x8*)__builtin_assume_aligned(brow + 16 * 20, 16);
          } else if (tpf == 21) {
            if (g7) Bq[21] = *(const f16x8*)__builtin_assume_aligned(brow + 16 * 21, 16);
          } else {
            Bq[tpf] = *(const f16x8*)__builtin_assume_aligned(brow + 16 * tpf, 16);
          }
        }
#pragma unroll
        for (int t = 0; t < 8; ++t) {
          const int rel = tau - 2 * t;
          if (rel < 0 || rel > 7) continue;
          if (rel == 0) {
            if (g0) acc[t] = __builtin_amdgcn_mfma_f32_32x32x16_f16(A[0], Bq[tau], acc[t], 0, 0, 0);
          } else if (rel == 6) {
            if (g6) acc[t] = __builtin_amdgcn_mfma_f32_32x32x16_f16(A[6], Bq[tau], acc[t], 0, 0, 0);
          } else if (rel == 7) {
            if (g7) acc[t] = __builtin_amdgcn_mfma_f32_32x32x16_f16(A[7], Bq[tau], acc[t], 0, 0, 0);
          } else {
            acc[t] = __builtin_amdgcn_mfma_f32_32x32x16_f16(A[rel], Bq[tau], acc[t], 0, 0, 0);
          }
        }
        // A prefetch for next ss into dead A[rel] (last use at tau = 14+rel)
        if (tau >= 14) {
          const int rn = tau - 14;
          if (rn == 0) {
            if (g0) A[0] = Awn[0];
          } else if (rn == 6) {
            if (g6) A[6] = Awn[6 * 64];
          } else if (rn == 7) {
            if (g7) A[7] = Awn[7 * 64];
          } else {
            A[rn] = Awn[rn * 64];
          }
        }
      }
    }

    // epilogue: for each (t, ol): gamma = 8t + 2w + ol
    const int c = 32 * pass + n;
#pragma unroll 1
    for (int t = 0; t < 8; ++t) {
#pragma unroll
      for (int ol = 0; ol < 2; ++ol) {
        const int gamma = 8 * t + 2 * w + ol;
        const float* qg = qsec + (size_t)gamma * 64 + c;
        float y0 = 0.f, y1 = 0.f, y2 = 0.f, y3 = 0.f;
#pragma unroll
        for (int e = 0; e < 8; ++e) {
          const int kk = (e & 3) + 8 * (e >> 2) + 4 * kap;
          const float cf = acc[t][ol * 8 + e] + lcb[e];
          y0 = fmaf(qg[(size_t)(kk) * 4096], cf, y0);
          y1 = fmaf(qg[(size_t)(16 + kk) * 4096], cf, y1);
          y2 = fmaf(qg[(size_t)(32 + kk) * 4096], cf, y2);
          y3 = fmaf(qg[(size_t)(48 + kk) * 4096], cf, y3);
        }
        y0 += __shfl_xor(y0, 32);
        y1 += __shfl_xor(y1, 32);
        y2 += __shfl_xor(y2, 32);
        y3 += __shfl_xor(y3, 32);
        const float s0 = kap ? y2 : y0;  // h = 2*kap
        const float s1 = kap ? y3 : y1;  // h = 2*kap + 1
        out[((size_t)(b * 256 + (2 * kap + 0) * 64 + dv)) * 4096 + gamma * 64 + c] = s0;
        out[((size_t)(b * 256 + (2 * kap + 1) * 64 + dv)) * 4096 + gamma * 64 + c] = s1;
      }
    }
  }
}

// ---------------------------------------------------------------------------
extern "C" void kernel_launch(void* const* d_in, const int* in_sizes, int n_in,
                              void* d_out, int out_size, void* d_ws, size_t ws_size,
                              hipStream_t stream) {
  const float* x       = (const float*)d_in[0];
  const float* w_q     = (const float*)d_in[1];
  const float* w_k     = (const float*)d_in[2];
  const float* w_v     = (const float*)d_in[3];
  const float* gamma_q = (const float*)d_in[4];
  const float* beta_q  = (const float*)d_in[5];
  const float* mean_q  = (const float*)d_in[6];
  const float* var_q   = (const float*)d_in[7];
  const float* gamma_v = (const float*)d_in[8];
  const float* beta_v  = (const float*)d_in[9];
  const float* mean_v  = (const float*)d_in[10];
  const float* var_v   = (const float*)d_in[11];
  const float* w_pos   = (const float*)d_in[12];
  const float* b_pos   = (const float*)d_in[13];

  float* ws = (float*)d_ws;
  float* proj = ws;                            // 16*384*4096 floats
  float* sb   = ws + 25165824;                 // 768 floats
  float* Lc   = sb + 768;                      // 16384 floats
  _Float16* Apack = (_Float16*)(Lc + 16384);   // 376832 halfs
  float* out = (float*)d_out;

  setup_kernel<<<1472, 256, 0, stream>>>(w_pos, gamma_q, beta_q, mean_q, var_q,
                                         gamma_v, beta_v, mean_v, var_v, sb, Apack);
  proj_gemm<<<dim3(64, 6, 16), 256, 0, stream>>>(x, w_q, w_k, w_v, sb, proj);
  softmax_k<<<1024, 256, 0, stream>>>(proj);
  lc_kernel<<<dim3(16, 16), 256, 0, stream>>>(proj, Lc);
  lambda_conv<<<dim3(64, 16), 256, 0, stream>>>(proj, Apack, Lc, b_pos, out);
}